// Round 17
// baseline (180.127 us; speedup 1.0000x reference)
//
#include <hip/hip_runtime.h>
#include <hip/hip_bf16.h>

// RNN cell: out[B,N] = tanh( concat(x,hidden)[B,K] @ W^T[K,N] + b[N] )
// M=16384, N=1024, K=2048, fp32 in/out.
// Pass 1: fp32->bf16 cvt+concat into ws.
// Pass 2 (r17 = r14 + full frag prefetch): 256x256 whole-tile GEMM, 16 waves
//   (4M x 4N, 64x64 out/wave). r16 measured 5513 cyc/tile vs content
//   2482 (MFMA) + ~2800 (LDS) -- serial. Cause: source order read-kk0 /
//   mfma-kk0 / read-kk1 / mfma-kk1 and no compiler hoist (VGPR=56).
//   Change: issue ALL 16 frag ds_reads (both kk) before any MFMA, named
//   regs (rule 20); stage after reads; MFMAs consume in read order so
//   fine-grained lgkmcnt starts kk0 MFMAs while kk1 reads stream.
//   Everything else identical to r16's verified kernel.

typedef __bf16 bf16_t;
typedef __bf16 bf16x8 __attribute__((ext_vector_type(8)));
typedef float  f32x4  __attribute__((ext_vector_type(4)));

#define M_GLOBAL 16384
#define N_GLOBAL 1024
#define K_GLOBAL 2048
#define IN_STRIDE 1024
#define NT 32

__device__ __forceinline__ float fast_tanh(float v) {
    float e = __expf(2.0f * v);
    return 1.0f - 2.0f * __builtin_amdgcn_rcpf(e + 1.0f);
}

// ---------------------------------------------------------------------------
// Pass 1: cvt + concat (~25 us measured; near L3-assisted BW floor).
// ---------------------------------------------------------------------------
#define XH_UNITS ((long long)M_GLOBAL * K_GLOBAL / 8)
#define W_UNITS  ((long long)N_GLOBAL * K_GLOBAL / 8)

__global__ __launch_bounds__(256)
void cvt_pass(const float* __restrict__ x, const float* __restrict__ h,
              const float* __restrict__ W,
              bf16_t* __restrict__ XHb, bf16_t* __restrict__ Wb)
{
    const long long total = XH_UNITS + W_UNITS;
    for (long long u = (long long)blockIdx.x * 256 + threadIdx.x; u < total;
         u += (long long)gridDim.x * 256) {
        const float* src;
        bf16_t* dst;
        if (u < XH_UNITS) {
            const long long e = u * 8;
            const int row = (int)(e >> 11);
            const int col = (int)(e & 2047);
            src = (col < 1024) ? (x + (long long)row * IN_STRIDE + col)
                               : (h + (long long)row * IN_STRIDE + (col - 1024));
            dst = XHb + e;
        } else {
            const long long e = (u - XH_UNITS) * 8;
            src = W + e;
            dst = Wb + e;
        }
        const float4 v0 = *(const float4*)src;
        const float4 v1 = *(const float4*)(src + 4);
        bf16x8 o;
        o[0] = (bf16_t)v0.x; o[1] = (bf16_t)v0.y;
        o[2] = (bf16_t)v0.z; o[3] = (bf16_t)v0.w;
        o[4] = (bf16_t)v1.x; o[5] = (bf16_t)v1.y;
        o[6] = (bf16_t)v1.z; o[7] = (bf16_t)v1.w;
        *(bf16x8*)dst = o;
    }
}

// ---------------------------------------------------------------------------
// Pass 2: 256x256 whole-tile GEMM, 16 waves of 64x64, full frag prefetch.
// LDS: 2 dbuf x {A0,A1,B0,B1} 128x64 halves = 128 KB (1 block/CU).
// Swizzle (0 conflicts, verified r7-r16): slot s of row r holds k-slot
// s^(r&7); applied on global SOURCE (gload_lds writes linearly) + ds_read.
// Race audit (as r13/r14): stage(t+1) issued within tile t; VM0 at end
// drains own loads; barrier after VM0 -> tile t+1 resident before any read.
// WAR: staged buffer was last read in tile t-1, closed by the t-1 barrier.
// ---------------------------------------------------------------------------
__device__ __forceinline__ void gload_lds16(const bf16_t* g, bf16_t* l) {
    __builtin_amdgcn_global_load_lds(
        (const __attribute__((address_space(1))) void*)g,
        (__attribute__((address_space(3))) void*)l, 16, 0, 0);
}

__global__ __launch_bounds__(1024)
void gemm_w16(const bf16_t* __restrict__ XHb, const bf16_t* __restrict__ Wb,
              const float* __restrict__ bias, float* __restrict__ out)
{
    __shared__ __align__(16) bf16_t lds[2 * 32768];   // 128 KB

    const int tid = threadIdx.x;
    // r13 XCD map (FETCH 135->49 MB): 4 blocks sharing an A-panel on one XCD.
    const int x = blockIdx.x & 7;
    const int g = blockIdx.x >> 3;
    const int bm = (x * 8 + (g & 7)) * 256;
    const int bn = (g >> 3) * 256;

    const int lane = tid & 63;
    const int wid  = tid >> 6;        // 0..15
    const int wm = wid >> 2;          // 0..3 (M quarter)
    const int wn = wid & 3;           // 0..3 (N quarter)
    const int lr = lane & 15;
    const int lk = lane >> 4;
    const int s7 = lr & 7;

    // staging: wave w covers rows w*8..w*8+7 of each part; source col
    // pre-swizzled (linear LDS dest, rule 21).
    const int srow = lane >> 3;
    const int scol = ((lane & 7) ^ srow) * 8;
    const bf16_t* aS = XHb + (size_t)(bm + wid * 8 + srow) * K_GLOBAL + scol;
    const bf16_t* bS = Wb  + (size_t)(bn + wid * 8 + srow) * K_GLOBAL + scol;

    // frag-read bases (elems): parts A0,A1,B0,B1 at part*8192 within dbuf.
    const int aRd = (wm >> 1) * 8192 + ((wm & 1) * 64 + lr) * 64;
    const int bRd = (2 + (wn >> 1)) * 8192 + ((wn & 1) * 64 + lr) * 64;
    const int sl0 = ((0 + lk) ^ s7) * 8;   // kk=0 swizzled slot (hoisted)
    const int sl1 = ((4 + lk) ^ s7) * 8;   // kk=1

    f32x4 acc[4][4];
#pragma unroll
    for (int i = 0; i < 4; ++i)
#pragma unroll
        for (int j = 0; j < 4; ++j)
            acc[i][j] = (f32x4){0.f, 0.f, 0.f, 0.f};

    // full-tile stage: one 1KB chunk per part per wave (4 gloads/thread)
#define STAGE_FULL(T, D) {                                                    \
    _Pragma("unroll")                                                         \
    for (int p_ = 0; p_ < 4; ++p_) {                                          \
        const bf16_t* g_ = ((p_ < 2) ? aS : bS)                               \
            + (size_t)((p_ & 1) * 128) * K_GLOBAL + (T) * 64;                 \
        gload_lds16(g_, lds + (D) * 32768 + p_ * 8192 + wid * 512);           \
    }                                                                         \
}

#define BAR() { asm volatile("" ::: "memory");                                \
                __builtin_amdgcn_s_barrier();                                 \
                asm volatile("" ::: "memory"); }
#define VM0() asm volatile("s_waitcnt vmcnt(0)" ::: "memory")

    // prologue: stage T0 -> dbuf0
    STAGE_FULL(0, 0);
    VM0();
    BAR();

    for (int t = 0; t < NT; ++t) {
        const bf16_t* lb = lds + (t & 1) * 32768;

        // ---- issue ALL 16 frag reads first (kk0 set, then kk1 set).
        // Named regs: every access compile-time-constant (rule 20).
        bf16x8 b00 = *(const bf16x8*)(lb + bRd + 0 * 1024 + sl0);
        bf16x8 b01 = *(const bf16x8*)(lb + bRd + 1 * 1024 + sl0);
        bf16x8 b02 = *(const bf16x8*)(lb + bRd + 2 * 1024 + sl0);
        bf16x8 b03 = *(const bf16x8*)(lb + bRd + 3 * 1024 + sl0);
        bf16x8 a00 = *(const bf16x8*)(lb + aRd + 0 * 1024 + sl0);
        bf16x8 a01 = *(const bf16x8*)(lb + aRd + 1 * 1024 + sl0);
        bf16x8 a02 = *(const bf16x8*)(lb + aRd + 2 * 1024 + sl0);
        bf16x8 a03 = *(const bf16x8*)(lb + aRd + 3 * 1024 + sl0);
        bf16x8 b10 = *(const bf16x8*)(lb + bRd + 0 * 1024 + sl1);
        bf16x8 b11 = *(const bf16x8*)(lb + bRd + 1 * 1024 + sl1);
        bf16x8 b12 = *(const bf16x8*)(lb + bRd + 2 * 1024 + sl1);
        bf16x8 b13 = *(const bf16x8*)(lb + bRd + 3 * 1024 + sl1);
        bf16x8 a10 = *(const bf16x8*)(lb + aRd + 0 * 1024 + sl1);
        bf16x8 a11 = *(const bf16x8*)(lb + aRd + 1 * 1024 + sl1);
        bf16x8 a12 = *(const bf16x8*)(lb + aRd + 2 * 1024 + sl1);
        bf16x8 a13 = *(const bf16x8*)(lb + aRd + 3 * 1024 + sl1);

        // ---- stage next tile (vmem; independent of lgkm reads above)
        if (t + 1 < NT) STAGE_FULL(t + 1, (t + 1) & 1);

        // ---- MFMAs in read order: kk0 cluster starts when the first 8
        // reads land (fine-grained lgkmcnt) while kk1 reads still stream.
        __builtin_amdgcn_s_setprio(1);
#define MF(A_, B_, M_, N_) \
    acc[M_][N_] = __builtin_amdgcn_mfma_f32_16x16x32_bf16(A_, B_, acc[M_][N_], 0, 0, 0)
        MF(a00, b00, 0, 0); MF(a00, b01, 0, 1); MF(a00, b02, 0, 2); MF(a00, b03, 0, 3);
        MF(a01, b00, 1, 0); MF(a01, b01, 1, 1); MF(a01, b02, 1, 2); MF(a01, b03, 1, 3);
        MF(a02, b00, 2, 0); MF(a02, b01, 2, 1); MF(a02, b02, 2, 2); MF(a02, b03, 2, 3);
        MF(a03, b00, 3, 0); MF(a03, b01, 3, 1); MF(a03, b02, 3, 2); MF(a03, b03, 3, 3);
        MF(a10, b10, 0, 0); MF(a10, b11, 0, 1); MF(a10, b12, 0, 2); MF(a10, b13, 0, 3);
        MF(a11, b10, 1, 0); MF(a11, b11, 1, 1); MF(a11, b12, 1, 2); MF(a11, b13, 1, 3);
        MF(a12, b10, 2, 0); MF(a12, b11, 2, 1); MF(a12, b12, 2, 2); MF(a12, b13, 2, 3);
        MF(a13, b10, 3, 0); MF(a13, b11, 3, 1); MF(a13, b12, 3, 2); MF(a13, b13, 3, 3);
#undef MF
        __builtin_amdgcn_s_setprio(0);

        if (t + 1 < NT) { VM0(); BAR(); }
    }

#undef STAGE_FULL
#undef BAR
#undef VM0

    // ---- epilogue: bias + tanh, fp32 store.
    // C/D layout: col = lane&15, row = (lane>>4)*4 + reg (verified r1-r16).
    float bv[4];
#pragma unroll
    for (int nf = 0; nf < 4; ++nf)
        bv[nf] = bias[bn + wn * 64 + nf * 16 + lr];
#pragma unroll
    for (int mf = 0; mf < 4; ++mf) {
#pragma unroll
        for (int nf = 0; nf < 4; ++nf) {
            const int col = bn + wn * 64 + nf * 16 + lr;
#pragma unroll
            for (int r = 0; r < 4; ++r) {
                const int row = bm + wm * 64 + mf * 16 + lk * 4 + r;
                out[(size_t)row * N_GLOBAL + col] = fast_tanh(acc[mf][nf][r] + bv[nf]);
            }
        }
    }
}

// ---------------------------------------------------------------------------
// Fallback (ws too small): round-3 verified fused kernel (~169 us).
// ---------------------------------------------------------------------------
#define FNT 32
__global__ __launch_bounds__(256, 2)
void rnncell_fused(const float* __restrict__ x, const float* __restrict__ h,
                   const float* __restrict__ W, const float* __restrict__ bias,
                   float* __restrict__ out)
{
    __shared__ __align__(16) bf16_t As[2][128 * 64];
    __shared__ __align__(16) bf16_t Bs[2][128 * 64];

    const int tid = threadIdx.x;
    const int bid = blockIdx.x;
    const int bm = (bid >> 3) * 128;
    const int bn = (bid & 7) * 128;

    const int lane = tid & 63;
    const int wid  = tid >> 6;
    const int wr = (wid >> 1) * 64;
    const int wc = (wid & 1) * 64;
    const int lr = lane & 15;
    const int lk = lane >> 4;

    const int row0 = tid >> 3;
    const int sl0  = tid & 7;

    f32x4 acc[4][4];
#pragma unroll
    for (int i = 0; i < 4; ++i)
#pragma unroll
        for (int j = 0; j < 4; ++j)
            acc[i][j] = (f32x4){0.f, 0.f, 0.f, 0.f};

    float4 la[4][2], lb[4][2];

#define F_LOAD_A(T) do {                                                      \
    const int k0_ = (T) * 64;                                                 \
    const float* sA_ = (k0_ < 1024)                                           \
        ? (x + (size_t)bm * IN_STRIDE + k0_)                                  \
        : (h + (size_t)bm * IN_STRIDE + (k0_ - 1024));                        \
    _Pragma("unroll")                                                         \
    for (int i_ = 0; i_ < 4; ++i_) {                                          \
        const float* pa_ = sA_ + (size_t)(row0 + i_ * 32) * IN_STRIDE + sl0 * 8; \
        la[i_][0] = *(const float4*)(pa_);                                    \
        la[i_][1] = *(const float4*)(pa_ + 4);                                \
    }                                                                         \
} while (0)

#define F_LOAD_B(T) do {                                                      \
    const float* sB_ = W + (size_t)bn * K_GLOBAL + (T) * 64;                  \
    _Pragma("unroll")                                                         \
    for (int i_ = 0; i_ < 4; ++i_) {                                          \
        const float* pb_ = sB_ + (size_t)(row0 + i_ * 32) * K_GLOBAL + sl0 * 8; \
        lb[i_][0] = *(const float4*)(pb_);                                    \
        lb[i_][1] = *(const float4*)(pb_ + 4);                                \
    }                                                                         \
} while (0)

    F_LOAD_A(0);
    F_LOAD_B(0);

    for (int t = 0; t < FNT; ++t) {
        bf16_t* __restrict__ Ab = As[t & 1];
        bf16_t* __restrict__ Bb = Bs[t & 1];

#pragma unroll
        for (int i = 0; i < 4; ++i) {
            const int row = row0 + i * 32;
            const int ssl = sl0 ^ (row & 7);
            bf16x8 va;
            va[0] = (bf16_t)la[i][0].x; va[1] = (bf16_t)la[i][0].y;
            va[2] = (bf16_t)la[i][0].z; va[3] = (bf16_t)la[i][0].w;
            va[4] = (bf16_t)la[i][1].x; va[5] = (bf16_t)la[i][1].y;
            va[6] = (bf16_t)la[i][1].z; va[7] = (bf16_t)la[i][1].w;
            *(bf16x8*)(Ab + row * 64 + ssl * 8) = va;
        }
#pragma unroll
        for (int i = 0; i < 4; ++i) {
            const int row = row0 + i * 32;
            const int ssl = sl0 ^ (row & 7);
            bf16x8 vb;
            vb[0] = (bf16_t)lb[i][0].x; vb[1] = (bf16_t)lb[i][0].y;
            vb[2] = (bf16_t)lb[i][0].z; vb[3] = (bf16_t)lb[i][0].w;
            vb[4] = (bf16_t)lb[i][1].x; vb[5] = (bf16_t)lb[i][1].y;
            vb[6] = (bf16_t)lb[i][1].z; vb[7] = (bf16_t)lb[i][1].w;
            *(bf16x8*)(Bb + row * 64 + ssl * 8) = vb;
        }

        __syncthreads();

        if (t + 1 < FNT) F_LOAD_A(t + 1);

#pragma unroll
        for (int kk = 0; kk < 2; ++kk) {
            bf16x8 af[4], bfr[4];
#pragma unroll
            for (int mf = 0; mf < 4; ++mf) {
                const int row = wr + mf * 16 + lr;
                const int sl  = (kk * 4 + lk) ^ (row & 7);
                af[mf] = *(const bf16x8*)(Ab + row * 64 + sl * 8);
            }
#pragma unroll
            for (int nf = 0; nf < 4; ++nf) {
                const int row = wc + nf * 16 + lr;
                const int sl  = (kk * 4 + lk) ^ (row & 7);
                bfr[nf] = *(const bf16x8*)(Bb + row * 64 + sl * 8);
            }
#pragma unroll
            for (int mf = 0; mf < 4; ++mf)
#pragma unroll
                for (int nf = 0; nf < 4; ++nf)
                    acc[mf][nf] = __builtin_amdgcn_mfma_f32_16x16x32_bf16(
                        af[mf], bfr[nf], acc[mf][nf], 0, 0, 0);
        }

        if (t + 1 < FNT) F_LOAD_B(t + 1);
    }
#undef F_LOAD_A
#undef F_LOAD_B

    float bv[4];
#pragma unroll
    for (int nf = 0; nf < 4; ++nf)
        bv[nf] = bias[bn + wc + nf * 16 + lr];
#pragma unroll
    for (int mf = 0; mf < 4; ++mf) {
#pragma unroll
        for (int nf = 0; nf < 4; ++nf) {
            const int col = bn + wc + nf * 16 + lr;
#pragma unroll
            for (int r = 0; r < 4; ++r) {
                const int row = bm + wr + mf * 16 + lk * 4 + r;
                out[(size_t)row * N_GLOBAL + col] = fast_tanh(acc[mf][nf][r] + bv[nf]);
            }
        }
    }
}

extern "C" void kernel_launch(void* const* d_in, const int* in_sizes, int n_in,
                              void* d_out, int out_size, void* d_ws, size_t ws_size,
                              hipStream_t stream) {
    (void)in_sizes; (void)n_in; (void)out_size;
    const float* x = (const float*)d_in[0];
    const float* h = (const float*)d_in[1];
    const float* W = (const float*)d_in[2];
    const float* b = (const float*)d_in[3];
    float* out = (float*)d_out;

    const size_t need = ((size_t)M_GLOBAL + N_GLOBAL) * K_GLOBAL * sizeof(bf16_t);
    if (ws_size >= need) {
        bf16_t* XHb = (bf16_t*)d_ws;
        bf16_t* Wb  = XHb + (size_t)M_GLOBAL * K_GLOBAL;
        cvt_pass<<<2048, 256, 0, stream>>>(x, h, W, XHb, Wb);
        gemm_w16<<<256, 1024, 0, stream>>>(XHb, Wb, b, out);
    } else {
        rnncell_fused<<<1024, 256, 0, stream>>>(x, h, W, b, out);
    }
}

// Round 18
// 99.938 us; speedup vs baseline: 1.8024x; 1.8024x over previous
//
#include <hip/hip_runtime.h>
#include <hip/hip_bf16.h>

// RNN cell: out[B,N] = tanh( concat(x,hidden)[B,K] @ W^T[K,N] + b[N] )
// M=16384, N=1024, K=2048, fp32 in/out.
// Pass 1: fp32->bf16 cvt+concat into ws.
// Pass 2 (r18 = r13 structure + full 24-frag prefetch): 256x256 whole-tile
//   GEMM, 512 threads = 8 waves (2M x 4N, 128x64 out/wave).
//   Occupancy-vs-ILP matrix so far:
//     r13: 8w, no prefetch  -> 91 us (TLP-starved, serial LDS/MFMA)
//     r16: 16w, no prefetch -> 73.5 us (TLP hides some, still serial)
//     r17: 16w, prefetch    -> SPILL (acc64 + frags64 > 128-reg cap)
//     r18: 8w, prefetch     -> 256-reg cap: acc128(AGPR) + frags96(VGPR)
//                              + addr ~25 = ~249: fits, ILP replaces TLP.
//   All 24 frag ds_reads issued as NAMED regs (rule 20) before any MFMA;
//   MFMAs consume in read order -> fine-grained lgkmcnt overlaps the LDS
//   stream (~2300 cyc) with the MFMA stream (~2065 cyc) within each wave.

typedef __bf16 bf16_t;
typedef __bf16 bf16x8 __attribute__((ext_vector_type(8)));
typedef float  f32x4  __attribute__((ext_vector_type(4)));

#define M_GLOBAL 16384
#define N_GLOBAL 1024
#define K_GLOBAL 2048
#define IN_STRIDE 1024
#define NT 32

__device__ __forceinline__ float fast_tanh(float v) {
    float e = __expf(2.0f * v);
    return 1.0f - 2.0f * __builtin_amdgcn_rcpf(e + 1.0f);
}

// ---------------------------------------------------------------------------
// Pass 1: cvt + concat (~25 us measured; near BW floor).
// ---------------------------------------------------------------------------
#define XH_UNITS ((long long)M_GLOBAL * K_GLOBAL / 8)
#define W_UNITS  ((long long)N_GLOBAL * K_GLOBAL / 8)

__global__ __launch_bounds__(256)
void cvt_pass(const float* __restrict__ x, const float* __restrict__ h,
              const float* __restrict__ W,
              bf16_t* __restrict__ XHb, bf16_t* __restrict__ Wb)
{
    const long long total = XH_UNITS + W_UNITS;
    for (long long u = (long long)blockIdx.x * 256 + threadIdx.x; u < total;
         u += (long long)gridDim.x * 256) {
        const float* src;
        bf16_t* dst;
        if (u < XH_UNITS) {
            const long long e = u * 8;
            const int row = (int)(e >> 11);
            const int col = (int)(e & 2047);
            src = (col < 1024) ? (x + (long long)row * IN_STRIDE + col)
                               : (h + (long long)row * IN_STRIDE + (col - 1024));
            dst = XHb + e;
        } else {
            const long long e = (u - XH_UNITS) * 8;
            src = W + e;
            dst = Wb + e;
        }
        const float4 v0 = *(const float4*)src;
        const float4 v1 = *(const float4*)(src + 4);
        bf16x8 o;
        o[0] = (bf16_t)v0.x; o[1] = (bf16_t)v0.y;
        o[2] = (bf16_t)v0.z; o[3] = (bf16_t)v0.w;
        o[4] = (bf16_t)v1.x; o[5] = (bf16_t)v1.y;
        o[6] = (bf16_t)v1.z; o[7] = (bf16_t)v1.w;
        *(bf16x8*)dst = o;
    }
}

// ---------------------------------------------------------------------------
// Pass 2: whole-tile GEMM, 8 waves of 128x64, full frag prefetch.
// LDS: 2 dbuf x {A0,A1,B0,B1} 128x64 halves = 128 KB (1 block/CU).
// Swizzle (0 conflicts, verified r7-r16): slot s of row r holds k-slot
// s^(r&7); applied on global SOURCE (gload_lds writes linearly) + ds_read.
// Race audit (r13): stage(t+1) issued within tile t; VM0 at end drains own
// loads; barrier after VM0 -> tile t+1 resident before any read. WAR: the
// staged buffer was last read in tile t-1, closed by the t-1 barrier.
// ---------------------------------------------------------------------------
__device__ __forceinline__ void gload_lds16(const bf16_t* g, bf16_t* l) {
    __builtin_amdgcn_global_load_lds(
        (const __attribute__((address_space(1))) void*)g,
        (__attribute__((address_space(3))) void*)l, 16, 0, 0);
}

__global__ __launch_bounds__(512, 2)
void gemm_p8(const bf16_t* __restrict__ XHb, const bf16_t* __restrict__ Wb,
             const float* __restrict__ bias, float* __restrict__ out)
{
    __shared__ __align__(16) bf16_t lds[2 * 32768];   // 128 KB

    const int tid = threadIdx.x;
    // r13 XCD map (FETCH 135->49 MB): 4 blocks sharing an A-panel on one XCD.
    const int x = blockIdx.x & 7;
    const int g = blockIdx.x >> 3;
    const int bm = (x * 8 + (g & 7)) * 256;
    const int bn = (g >> 3) * 256;

    const int lane = tid & 63;
    const int wid  = tid >> 6;        // 0..7
    const int wm = wid >> 2;          // 0..1 (M half)
    const int wn = wid & 3;           // 0..3 (N quarter)
    const int lr = lane & 15;
    const int lk = lane >> 4;
    const int s7 = lr & 7;

    // staging: wave stages 2 chunks of 8 rows per part (8 gloads/thread);
    // source col pre-swizzled (linear LDS dest, rule 21).
    const int srow = lane >> 3;
    const int scol = ((lane & 7) ^ srow) * 8;
    const int c0   = wid * 2;
    const bf16_t* aS = XHb + (size_t)(bm + c0 * 8 + srow) * K_GLOBAL + scol;
    const bf16_t* bS = Wb  + (size_t)(bn + c0 * 8 + srow) * K_GLOBAL + scol;

    // frag-read bases (elems): parts A0,A1,B0,B1 at part*8192 within dbuf.
    const int aRd = wm * 8192 + lr * 64;
    const int bRd = (2 + (wn >> 1)) * 8192 + ((wn & 1) * 64 + lr) * 64;
    const int sl0 = ((0 + lk) ^ s7) * 8;   // kk=0 swizzled slot
    const int sl1 = ((4 + lk) ^ s7) * 8;   // kk=1

    f32x4 acc[8][4];
#pragma unroll
    for (int i = 0; i < 8; ++i)
#pragma unroll
        for (int j = 0; j < 4; ++j)
            acc[i][j] = (f32x4){0.f, 0.f, 0.f, 0.f};

#define STAGE_FULL(T, D) {                                                    \
    _Pragma("unroll")                                                         \
    for (int p_ = 0; p_ < 4; ++p_) {                                          \
        const bf16_t* g_ = ((p_ < 2) ? aS : bS)                               \
            + (size_t)((p_ & 1) * 128) * K_GLOBAL + (T) * 64;                 \
        bf16_t* l_ = lds + (D) * 32768 + p_ * 8192 + c0 * 512;                \
        gload_lds16(g_, l_);                                                  \
        gload_lds16(g_ + (size_t)8 * K_GLOBAL, l_ + 512);                     \
    }                                                                         \
}

#define BAR() { asm volatile("" ::: "memory");                                \
                __builtin_amdgcn_s_barrier();                                 \
                asm volatile("" ::: "memory"); }
#define VM0() asm volatile("s_waitcnt vmcnt(0)" ::: "memory")

    // prologue: stage T0 -> dbuf0
    STAGE_FULL(0, 0);
    VM0();
    BAR();

    for (int t = 0; t < NT; ++t) {
        const bf16_t* lb = lds + (t & 1) * 32768;

        // ---- all 24 frag reads first, named regs (96 VGPR peak).
        // kk0 set (consumed first), then kk1 set.
        bf16x8 b00 = *(const bf16x8*)(lb + bRd + 0 * 1024 + sl0);
        bf16x8 b01 = *(const bf16x8*)(lb + bRd + 1 * 1024 + sl0);
        bf16x8 b02 = *(const bf16x8*)(lb + bRd + 2 * 1024 + sl0);
        bf16x8 b03 = *(const bf16x8*)(lb + bRd + 3 * 1024 + sl0);
        bf16x8 a00 = *(const bf16x8*)(lb + aRd + 0 * 1024 + sl0);
        bf16x8 a01 = *(const bf16x8*)(lb + aRd + 1 * 1024 + sl0);
        bf16x8 a02 = *(const bf16x8*)(lb + aRd + 2 * 1024 + sl0);
        bf16x8 a03 = *(const bf16x8*)(lb + aRd + 3 * 1024 + sl0);
        bf16x8 a04 = *(const bf16x8*)(lb + aRd + 4 * 1024 + sl0);
        bf16x8 a05 = *(const bf16x8*)(lb + aRd + 5 * 1024 + sl0);
        bf16x8 a06 = *(const bf16x8*)(lb + aRd + 6 * 1024 + sl0);
        bf16x8 a07 = *(const bf16x8*)(lb + aRd + 7 * 1024 + sl0);
        bf16x8 b10 = *(const bf16x8*)(lb + bRd + 0 * 1024 + sl1);
        bf16x8 b11 = *(const bf16x8*)(lb + bRd + 1 * 1024 + sl1);
        bf16x8 b12 = *(const bf16x8*)(lb + bRd + 2 * 1024 + sl1);
        bf16x8 b13 = *(const bf16x8*)(lb + bRd + 3 * 1024 + sl1);
        bf16x8 a10 = *(const bf16x8*)(lb + aRd + 0 * 1024 + sl1);
        bf16x8 a11 = *(const bf16x8*)(lb + aRd + 1 * 1024 + sl1);
        bf16x8 a12 = *(const bf16x8*)(lb + aRd + 2 * 1024 + sl1);
        bf16x8 a13 = *(const bf16x8*)(lb + aRd + 3 * 1024 + sl1);
        bf16x8 a14 = *(const bf16x8*)(lb + aRd + 4 * 1024 + sl1);
        bf16x8 a15 = *(const bf16x8*)(lb + aRd + 5 * 1024 + sl1);
        bf16x8 a16 = *(const bf16x8*)(lb + aRd + 6 * 1024 + sl1);
        bf16x8 a17 = *(const bf16x8*)(lb + aRd + 7 * 1024 + sl1);

        // ---- stage next tile (vmem counter; independent of lgkm reads)
        if (t + 1 < NT) STAGE_FULL(t + 1, (t + 1) & 1);

        // ---- MFMAs in read order; kk0 cluster starts once its 12 reads
        // land while the 12 kk1 reads still stream through the LDS pipe.
        __builtin_amdgcn_s_setprio(1);
#define MF(A_, B_, M_, N_) \
    acc[M_][N_] = __builtin_amdgcn_mfma_f32_16x16x32_bf16(A_, B_, acc[M_][N_], 0, 0, 0)
        MF(a00, b00, 0, 0); MF(a00, b01, 0, 1); MF(a00, b02, 0, 2); MF(a00, b03, 0, 3);
        MF(a01, b00, 1, 0); MF(a01, b01, 1, 1); MF(a01, b02, 1, 2); MF(a01, b03, 1, 3);
        MF(a02, b00, 2, 0); MF(a02, b01, 2, 1); MF(a02, b02, 2, 2); MF(a02, b03, 2, 3);
        MF(a03, b00, 3, 0); MF(a03, b01, 3, 1); MF(a03, b02, 3, 2); MF(a03, b03, 3, 3);
        MF(a04, b00, 4, 0); MF(a04, b01, 4, 1); MF(a04, b02, 4, 2); MF(a04, b03, 4, 3);
        MF(a05, b00, 5, 0); MF(a05, b01, 5, 1); MF(a05, b02, 5, 2); MF(a05, b03, 5, 3);
        MF(a06, b00, 6, 0); MF(a06, b01, 6, 1); MF(a06, b02, 6, 2); MF(a06, b03, 6, 3);
        MF(a07, b00, 7, 0); MF(a07, b01, 7, 1); MF(a07, b02, 7, 2); MF(a07, b03, 7, 3);
        MF(a10, b10, 0, 0); MF(a10, b11, 0, 1); MF(a10, b12, 0, 2); MF(a10, b13, 0, 3);
        MF(a11, b10, 1, 0); MF(a11, b11, 1, 1); MF(a11, b12, 1, 2); MF(a11, b13, 1, 3);
        MF(a12, b10, 2, 0); MF(a12, b11, 2, 1); MF(a12, b12, 2, 2); MF(a12, b13, 2, 3);
        MF(a13, b10, 3, 0); MF(a13, b11, 3, 1); MF(a13, b12, 3, 2); MF(a13, b13, 3, 3);
        MF(a14, b10, 4, 0); MF(a14, b11, 4, 1); MF(a14, b12, 4, 2); MF(a14, b13, 4, 3);
        MF(a15, b10, 5, 0); MF(a15, b11, 5, 1); MF(a15, b12, 5, 2); MF(a15, b13, 5, 3);
        MF(a16, b10, 6, 0); MF(a16, b11, 6, 1); MF(a16, b12, 6, 2); MF(a16, b13, 6, 3);
        MF(a17, b10, 7, 0); MF(a17, b11, 7, 1); MF(a17, b12, 7, 2); MF(a17, b13, 7, 3);
#undef MF
        __builtin_amdgcn_s_setprio(0);

        if (t + 1 < NT) { VM0(); BAR(); }
    }

#undef STAGE_FULL
#undef BAR
#undef VM0

    // ---- epilogue: bias + tanh, fp32 store.
    // C/D layout: col = lane&15, row = (lane>>4)*4 + reg (verified r1-r16).
    float bv[4];
#pragma unroll
    for (int nf = 0; nf < 4; ++nf)
        bv[nf] = bias[bn + wn * 64 + nf * 16 + lr];
#pragma unroll
    for (int mf = 0; mf < 8; ++mf) {
#pragma unroll
        for (int nf = 0; nf < 4; ++nf) {
            const int col = bn + wn * 64 + nf * 16 + lr;
#pragma unroll
            for (int r = 0; r < 4; ++r) {
                const int row = bm + wm * 128 + mf * 16 + lk * 4 + r;
                out[(size_t)row * N_GLOBAL + col] = fast_tanh(acc[mf][nf][r] + bv[nf]);
            }
        }
    }
}

// ---------------------------------------------------------------------------
// Fallback (ws too small): round-3 verified fused kernel (~169 us).
// ---------------------------------------------------------------------------
#define FNT 32
__global__ __launch_bounds__(256, 2)
void rnncell_fused(const float* __restrict__ x, const float* __restrict__ h,
                   const float* __restrict__ W, const float* __restrict__ bias,
                   float* __restrict__ out)
{
    __shared__ __align__(16) bf16_t As[2][128 * 64];
    __shared__ __align__(16) bf16_t Bs[2][128 * 64];

    const int tid = threadIdx.x;
    const int bid = blockIdx.x;
    const int bm = (bid >> 3) * 128;
    const int bn = (bid & 7) * 128;

    const int lane = tid & 63;
    const int wid  = tid >> 6;
    const int wr = (wid >> 1) * 64;
    const int wc = (wid & 1) * 64;
    const int lr = lane & 15;
    const int lk = lane >> 4;

    const int row0 = tid >> 3;
    const int sl0  = tid & 7;

    f32x4 acc[4][4];
#pragma unroll
    for (int i = 0; i < 4; ++i)
#pragma unroll
        for (int j = 0; j < 4; ++j)
            acc[i][j] = (f32x4){0.f, 0.f, 0.f, 0.f};

    float4 la[4][2], lb[4][2];

#define F_LOAD_A(T) do {                                                      \
    const int k0_ = (T) * 64;                                                 \
    const float* sA_ = (k0_ < 1024)                                           \
        ? (x + (size_t)bm * IN_STRIDE + k0_)                                  \
        : (h + (size_t)bm * IN_STRIDE + (k0_ - 1024));                        \
    _Pragma("unroll")                                                         \
    for (int i_ = 0; i_ < 4; ++i_) {                                          \
        const float* pa_ = sA_ + (size_t)(row0 + i_ * 32) * IN_STRIDE + sl0 * 8; \
        la[i_][0] = *(const float4*)(pa_);                                    \
        la[i_][1] = *(const float4*)(pa_ + 4);                                \
    }                                                                         \
} while (0)

#define F_LOAD_B(T) do {                                                      \
    const float* sB_ = W + (size_t)bn * K_GLOBAL + (T) * 64;                  \
    _Pragma("unroll")                                                         \
    for (int i_ = 0; i_ < 4; ++i_) {                                          \
        const float* pb_ = sB_ + (size_t)(row0 + i_ * 32) * K_GLOBAL + sl0 * 8; \
        lb[i_][0] = *(const float4*)(pb_);                                    \
        lb[i_][1] = *(const float4*)(pb_ + 4);                                \
    }                                                                         \
} while (0)

    F_LOAD_A(0);
    F_LOAD_B(0);

    for (int t = 0; t < FNT; ++t) {
        bf16_t* __restrict__ Ab = As[t & 1];
        bf16_t* __restrict__ Bb = Bs[t & 1];

#pragma unroll
        for (int i = 0; i < 4; ++i) {
            const int row = row0 + i * 32;
            const int ssl = sl0 ^ (row & 7);
            bf16x8 va;
            va[0] = (bf16_t)la[i][0].x; va[1] = (bf16_t)la[i][0].y;
            va[2] = (bf16_t)la[i][0].z; va[3] = (bf16_t)la[i][0].w;
            va[4] = (bf16_t)la[i][1].x; va[5] = (bf16_t)la[i][1].y;
            va[6] = (bf16_t)la[i][1].z; va[7] = (bf16_t)la[i][1].w;
            *(bf16x8*)(Ab + row * 64 + ssl * 8) = va;
        }
#pragma unroll
        for (int i = 0; i < 4; ++i) {
            const int row = row0 + i * 32;
            const int ssl = sl0 ^ (row & 7);
            bf16x8 vb;
            vb[0] = (bf16_t)lb[i][0].x; vb[1] = (bf16_t)lb[i][0].y;
            vb[2] = (bf16_t)lb[i][0].z; vb[3] = (bf16_t)lb[i][0].w;
            vb[4] = (bf16_t)lb[i][1].x; vb[5] = (bf16_t)lb[i][1].y;
            vb[6] = (bf16_t)lb[i][1].z; vb[7] = (bf16_t)lb[i][1].w;
            *(bf16x8*)(Bb + row * 64 + ssl * 8) = vb;
        }

        __syncthreads();

        if (t + 1 < FNT) F_LOAD_A(t + 1);

#pragma unroll
        for (int kk = 0; kk < 2; ++kk) {
            bf16x8 af[4], bfr[4];
#pragma unroll
            for (int mf = 0; mf < 4; ++mf) {
                const int row = wr + mf * 16 + lr;
                const int sl  = (kk * 4 + lk) ^ (row & 7);
                af[mf] = *(const bf16x8*)(Ab + row * 64 + sl * 8);
            }
#pragma unroll
            for (int nf = 0; nf < 4; ++nf) {
                const int row = wc + nf * 16 + lr;
                const int sl  = (kk * 4 + lk) ^ (row & 7);
                bfr[nf] = *(const bf16x8*)(Bb + row * 64 + sl * 8);
            }
#pragma unroll
            for (int mf = 0; mf < 4; ++mf)
#pragma unroll
                for (int nf = 0; nf < 4; ++nf)
                    acc[mf][nf] = __builtin_amdgcn_mfma_f32_16x16x32_bf16(
                        af[mf], bfr[nf], acc[mf][nf], 0, 0, 0);
        }

        if (t + 1 < FNT) F_LOAD_B(t + 1);
    }
#undef F_LOAD_A
#undef F_LOAD_B

    float bv[4];
#pragma unroll
    for (int nf = 0; nf < 4; ++nf)
        bv[nf] = bias[bn + wc + nf * 16 + lr];
#pragma unroll
    for (int mf = 0; mf < 4; ++mf) {
#pragma unroll
        for (int nf = 0; nf < 4; ++nf) {
            const int col = bn + wc + nf * 16 + lr;
#pragma unroll
            for (int r = 0; r < 4; ++r) {
                const int row = bm + wr + mf * 16 + lk * 4 + r;
                out[(size_t)row * N_GLOBAL + col] = fast_tanh(acc[mf][nf][r] + bv[nf]);
            }
        }
    }
}

extern "C" void kernel_launch(void* const* d_in, const int* in_sizes, int n_in,
                              void* d_out, int out_size, void* d_ws, size_t ws_size,
                              hipStream_t stream) {
    (void)in_sizes; (void)n_in; (void)out_size;
    const float* x = (const float*)d_in[0];
    const float* h = (const float*)d_in[1];
    const float* W = (const float*)d_in[2];
    const float* b = (const float*)d_in[3];
    float* out = (float*)d_out;

    const size_t need = ((size_t)M_GLOBAL + N_GLOBAL) * K_GLOBAL * sizeof(bf16_t);
    if (ws_size >= need) {
        bf16_t* XHb = (bf16_t*)d_ws;
        bf16_t* Wb  = XHb + (size_t)M_GLOBAL * K_GLOBAL;
        cvt_pass<<<2048, 256, 0, stream>>>(x, h, W, XHb, Wb);
        gemm_p8<<<256, 512, 0, stream>>>(XHb, Wb, b, out);
    } else {
        rnncell_fused<<<1024, 256, 0, stream>>>(x, h, W, b, out);
    }
}